// Round 4
// baseline (555.604 us; speedup 1.0000x reference)
//
#include <hip/hip_runtime.h>
#include <math.h>

// ---------------------------------------------------------------------------
// GATv2 block: LN+ReLU -> x_l/x_r GEMMs (split-bf16 MFMA, 3-term fp32 emu) ->
// CSR build -> fused score+softmax+aggregate (no max-sub) -> head mean+bias.
// ---------------------------------------------------------------------------

typedef __bf16 bf16x8 __attribute__((ext_vector_type(8)));
typedef float f32x4 __attribute__((ext_vector_type(4)));

static __device__ __forceinline__ unsigned short f2bf(float f) {
  union { float f; unsigned u; } v;
  v.f = f;
  const unsigned r = v.u + 0x7fffu + ((v.u >> 16) & 1u);  // RNE
  return (unsigned short)(r >> 16);
}
static __device__ __forceinline__ float bf2f(unsigned short h) {
  union { float f; unsigned u; } v;
  v.u = ((unsigned)h) << 16;
  return v.f;
}

// ---------------- K0: split W into bf16 hi/lo, B-fragment layout -----------
// packed[(mat*4 + kb)*128*32 + c*32 + (k&31)], mat 0=Wl 1=Wr.
__global__ __launch_bounds__(256) void pack_w_k(
    const float* __restrict__ Wl, const float* __restrict__ Wr,
    unsigned short* __restrict__ wph, unsigned short* __restrict__ wpl) {
  const int idx = blockIdx.x * 256 + threadIdx.x;  // 0..32767
  const int mat = idx >> 14;
  const int rem = idx & 16383;   // k*128 + c
  const int k = rem >> 7;
  const int c = rem & 127;
  const float v = (mat ? Wr : Wl)[rem];
  const unsigned short h = f2bf(v);
  const unsigned short lo = f2bf(v - bf2f(h));
  const int po = ((mat * 4 + (k >> 5)) * 128 + c) * 32 + (k & 31);
  wph[po] = h;
  wpl[po] = lo;
}

// ---------------- K1: LN+ReLU + dual GEMM via mfma_f32_16x16x32_bf16 -------
// Block: 64 nodes x 256 out-cols (xl 128 | xr 128). 4 waves, one 64x64 each.
// A = xh split hi/lo in LDS (stride 136 shorts: 2-way banks = free).
// D = Ah*Bh + Al*Bh + Ah*Bl  (~fp32 precision; Al*Bl term ~2^-18, dropped).
__global__ __launch_bounds__(256, 4) void ln_gemm_mfma_k(
    const float* __restrict__ x, const float* __restrict__ gamma,
    const float* __restrict__ beta,
    const unsigned short* __restrict__ wph,
    const unsigned short* __restrict__ wpl,
    const float* __restrict__ bl, const float* __restrict__ br,
    float* __restrict__ xl, float* __restrict__ xr, int n) {
  __shared__ unsigned short ah[64 * 136];
  __shared__ unsigned short al[64 * 136];

  const int t = threadIdx.x;
  const int blk = blockIdx.x * 64;

  // ---- LN + ReLU + hi/lo split (all in registers; 4 lanes per node) ----
  {
    const int r = t >> 2, q = t & 3;
    const int node = blk + r;
    float4 v[8];
    float s = 0.f, s2 = 0.f;
    const float* xrow = x + (size_t)node * 128;
#pragma unroll
    for (int rep = 0; rep < 8; rep++) {
      float4 f = make_float4(0.f, 0.f, 0.f, 0.f);
      if (node < n) f = *(const float4*)(xrow + 4 * q + 16 * rep);
      v[rep] = f;
      s += f.x + f.y + f.z + f.w;
      s2 += f.x * f.x + f.y * f.y + f.z * f.z + f.w * f.w;
    }
    s += __shfl_xor(s, 1);  s += __shfl_xor(s, 2);
    s2 += __shfl_xor(s2, 1); s2 += __shfl_xor(s2, 2);
    const float mu = s * (1.f / 128.f);
    const float rs = rsqrtf(s2 * (1.f / 128.f) - mu * mu + 1e-5f);
#pragma unroll
    for (int rep = 0; rep < 8; rep++) {
      const int k0 = 4 * q + 16 * rep;
      const float4 g4 = *(const float4*)(gamma + k0);
      const float4 b4 = *(const float4*)(beta + k0);
      const float ev[4] = {v[rep].x, v[rep].y, v[rep].z, v[rep].w};
      const float gv[4] = {g4.x, g4.y, g4.z, g4.w};
      const float bv[4] = {b4.x, b4.y, b4.z, b4.w};
      unsigned short hs[4], ls[4];
#pragma unroll
      for (int i2 = 0; i2 < 4; i2++) {
        float xv = (ev[i2] - mu) * rs * gv[i2] + bv[i2];
        xv = fmaxf(xv, 0.f);
        const unsigned short h = f2bf(xv);
        hs[i2] = h;
        ls[i2] = f2bf(xv - bf2f(h));
      }
      *(ushort4*)(&ah[r * 136 + k0]) = make_ushort4(hs[0], hs[1], hs[2], hs[3]);
      *(ushort4*)(&al[r * 136 + k0]) = make_ushort4(ls[0], ls[1], ls[2], ls[3]);
    }
  }
  __syncthreads();

  // ---- MFMA phase ----
  const int lane = t & 63;
  const int w = t >> 6;
  const int mat = w >> 1;           // 0 -> xl, 1 -> xr
  const int cbase = (w & 1) * 64;   // col offset within the 128-wide matrix
  const int m16 = lane & 15;
  const int quad = lane >> 4;
  float* const outp = mat ? xr : xl;
  const float* const biasp = mat ? br : bl;

#pragma unroll
  for (int ct = 0; ct < 4; ct++) {
    const int c = cbase + ct * 16 + m16;
    bf16x8 Bh[4], Bl8[4];
#pragma unroll
    for (int kb = 0; kb < 4; kb++) {
      const int bo = ((mat * 4 + kb) * 128 + c) * 32 + quad * 8;
      Bh[kb]  = *(const bf16x8*)(wph + bo);
      Bl8[kb] = *(const bf16x8*)(wpl + bo);
    }
    const float bc = biasp[c];
#pragma unroll
    for (int rt = 0; rt < 4; rt++) {
      f32x4 a = {0.f, 0.f, 0.f, 0.f};
#pragma unroll
      for (int kb = 0; kb < 4; kb++) {
        const int ao = (rt * 16 + m16) * 136 + kb * 32 + quad * 8;
        const bf16x8 Ah  = *(const bf16x8*)(ah + ao);
        const bf16x8 Al8 = *(const bf16x8*)(al + ao);
        a = __builtin_amdgcn_mfma_f32_16x16x32_bf16(Ah,  Bh[kb],  a, 0, 0, 0);
        a = __builtin_amdgcn_mfma_f32_16x16x32_bf16(Al8, Bh[kb],  a, 0, 0, 0);
        a = __builtin_amdgcn_mfma_f32_16x16x32_bf16(Ah,  Bl8[kb], a, 0, 0, 0);
      }
      // C/D: col = lane&15, row = quad*4 + reg  [m89-verified]
#pragma unroll
      for (int g = 0; g < 4; g++) {
        const int row = blk + rt * 16 + quad * 4 + g;
        if (row < n) outp[(size_t)row * 128 + c] = a[g] + bc;
      }
    }
  }
}

// ---------------- K2: in-degree histogram (edges only; +1/node in scan) ----
__global__ __launch_bounds__(256) void degree_k(const int* __restrict__ dst_arr,
                                                int* __restrict__ deg, int E) {
  const int base = (blockIdx.x * 256 + threadIdx.x) * 4;
  if (base >= E) return;
  if (base + 4 <= E) {
    const int4 d4 = *(const int4*)(dst_arr + base);
    atomicAdd(&deg[d4.x], 1);
    atomicAdd(&deg[d4.y], 1);
    atomicAdd(&deg[d4.z], 1);
    atomicAdd(&deg[d4.w], 1);
  } else {
    for (int k = base; k < E; k++) atomicAdd(&deg[dst_arr[k]], 1);
  }
}

// ---------------- K3a/b/c: exclusive scan over (deg+1) -> offsets ----------
__global__ __launch_bounds__(256) void scan1_k(const int* __restrict__ deg,
                                               int* __restrict__ offsets,
                                               int* __restrict__ blocksums,
                                               int n) {
  __shared__ int lds[256];
  const int t = threadIdx.x;
  const int base = blockIdx.x * 1024 + t * 4;
  int v[4];
  int s = 0;
#pragma unroll
  for (int j = 0; j < 4; j++) {
    v[j] = (base + j < n) ? (deg[base + j] + 1) : 0;  // +1 = self-loop
    s += v[j];
  }
  lds[t] = s;
  __syncthreads();
  for (int off = 1; off < 256; off <<= 1) {
    int xv = 0;
    if (t >= off) xv = lds[t - off];
    __syncthreads();
    lds[t] += xv;
    __syncthreads();
  }
  const int incl = lds[t];
  if (t == 255) blocksums[blockIdx.x] = incl;
  int run = incl - s;  // exclusive
#pragma unroll
  for (int j = 0; j < 4; j++) {
    if (base + j < n) offsets[base + j] = run;
    run += v[j];
  }
}

__global__ __launch_bounds__(128) void scan2_k(int* __restrict__ blocksums,
                                               int nb) {
  __shared__ int lds[128];
  const int t = threadIdx.x;
  const int s = (t < nb) ? blocksums[t] : 0;
  lds[t] = s;
  __syncthreads();
  for (int off = 1; off < 128; off <<= 1) {
    int xv = 0;
    if (t >= off) xv = lds[t - off];
    __syncthreads();
    lds[t] += xv;
    __syncthreads();
  }
  if (t < nb) blocksums[t] = lds[t] - s;  // exclusive, in place
}

__global__ __launch_bounds__(256) void scan3_k(int* __restrict__ offsets,
                                               int* __restrict__ cursor,
                                               const int* __restrict__ blocksums,
                                               int n, int total) {
  const int base = blockIdx.x * 1024 + threadIdx.x * 4;
  const int add = blocksums[blockIdx.x];
#pragma unroll
  for (int j = 0; j < 4; j++) {
    if (base + j < n) {
      const int o = offsets[base + j] + add;
      offsets[base + j] = o;
      cursor[base + j] = o;
    }
  }
  if (blockIdx.x == 0 && threadIdx.x == 0) offsets[n] = total;
}

// ---------------- K4: CSR fill (edges + self-loops), 4 per thread ----------
__global__ __launch_bounds__(256) void fill_k(const int* __restrict__ ei,
                                              int* __restrict__ cursor,
                                              int* __restrict__ csr_src,
                                              int E, int N) {
  const int base = (blockIdx.x * 256 + threadIdx.x) * 4;
  if (base < E) {
    if (base + 4 <= E) {
      const int4 s4 = *(const int4*)(ei + base);
      const int4 d4 = *(const int4*)(ei + E + base);
      csr_src[atomicAdd(&cursor[d4.x], 1)] = s4.x;
      csr_src[atomicAdd(&cursor[d4.y], 1)] = s4.y;
      csr_src[atomicAdd(&cursor[d4.z], 1)] = s4.z;
      csr_src[atomicAdd(&cursor[d4.w], 1)] = s4.w;
    } else {
      for (int k = base; k < E; k++)
        csr_src[atomicAdd(&cursor[ei[E + k]], 1)] = ei[k];
    }
  }
  // self-loops
#pragma unroll
  for (int k = 0; k < 4; k++) {
    const int v = base + k;
    if (v < N) csr_src[atomicAdd(&cursor[v], 1)] = v;
  }
}

// ---------------- K5: fused score + softmax + aggregate (wave/node) --------
__global__ __launch_bounds__(256) void agg_fused_k(
    const float* __restrict__ xl, const float* __restrict__ xr,
    const float* __restrict__ att, const int* __restrict__ csr_src,
    const int* __restrict__ offsets, const float* __restrict__ bias,
    float* __restrict__ out, int n) {
  __shared__ float att_s[128];
  const int t = threadIdx.x;
  if (t < 128) att_s[t] = att[t];
  __syncthreads();

  const int wid = t >> 6;
  const int lane = t & 63;
  const int i = blockIdx.x * 4 + wid;
  if (i >= n) return;
  const int c = lane * 2;
  const int off = offsets[i];
  const int end = offsets[i + 1];

  const float2 b2 = *(const float2*)(bias + (c & 31));
  const float2 xr2 = *(const float2*)(xr + (size_t)i * 128 + c);
  const float2 at2 = *(const float2*)(att_s + c);

  float den = 0.f, accx = 0.f, accy = 0.f;

  float2 xvA[4];
#pragma unroll
  for (int k = 0; k < 4; k++) {
    const int jj = off + k < end ? off + k : end - 1;
    const int s = csr_src[jj];
    xvA[k] = *(const float2*)(xl + (size_t)s * 128 + c);
  }

  for (int j = off; j < end; j += 4) {
    float2 xv[4];
#pragma unroll
    for (int k = 0; k < 4; k++) xv[k] = xvA[k];
    const int jn = j + 4;
    if (jn < end) {
#pragma unroll
      for (int k = 0; k < 4; k++) {
        const int jj = jn + k < end ? jn + k : end - 1;
        const int s = csr_src[jj];
        xvA[k] = *(const float2*)(xl + (size_t)s * 128 + c);
      }
    }

    float p[4];
#pragma unroll
    for (int k = 0; k < 4; k++) {
      const float vx = xv[k].x + xr2.x;
      const float vy = xv[k].y + xr2.y;
      const float lx = fmaxf(vx, 0.2f * vx);
      const float ly = fmaxf(vy, 0.2f * vy);
      p[k] = fmaf(lx, at2.x, ly * at2.y);
    }
#pragma unroll
    for (int d = 1; d <= 8; d <<= 1) {
#pragma unroll
      for (int k = 0; k < 4; k++) p[k] += __shfl_xor(p[k], d);
    }
#pragma unroll
    for (int k = 0; k < 4; k++) {
      const float w = (j + k < end) ? __expf(p[k]) : 0.f;
      den += w;
      accx = fmaf(w, xv[k].x, accx);
      accy = fmaf(w, xv[k].y, accy);
    }
  }

  const float rd = 1.0f / (den + 1e-16f);
  accx *= rd;
  accy *= rd;
  accx += __shfl_xor(accx, 16); accy += __shfl_xor(accy, 16);
  accx += __shfl_xor(accx, 32); accy += __shfl_xor(accy, 32);
  if (lane < 16) {
    *(float2*)(out + (size_t)i * 32 + c) =
        make_float2(accx * 0.25f + b2.x, accy * 0.25f + b2.y);
  }
}

// ---------------------------------------------------------------------------
extern "C" void kernel_launch(void* const* d_in, const int* in_sizes, int n_in,
                              void* d_out, int out_size, void* d_ws,
                              size_t ws_size, hipStream_t stream) {
  const float* x     = (const float*)d_in[0];
  const int*   ei    = (const int*)d_in[1];
  const float* gamma = (const float*)d_in[2];
  const float* beta  = (const float*)d_in[3];
  const float* Wl    = (const float*)d_in[4];
  const float* bl    = (const float*)d_in[5];
  const float* Wr    = (const float*)d_in[6];
  const float* br    = (const float*)d_in[7];
  const float* att   = (const float*)d_in[8];
  const float* bias  = (const float*)d_in[9];
  float* out = (float*)d_out;

  const int N = in_sizes[0] / 128;
  const int E = in_sizes[1] / 2;
  const int M = E + N;

  char* p = (char*)d_ws;
  size_t o = 0;
  auto alloc = [&](size_t bytes) -> void* {
    void* r = (void*)(p + o);
    o = (o + bytes + 255) & ~(size_t)255;
    return r;
  };
  float* xl      = (float*)alloc((size_t)N * 128 * 4);
  float* xr      = (float*)alloc((size_t)N * 128 * 4);
  int*   csr_src = (int*)alloc((size_t)M * 4);
  int*   deg     = (int*)alloc((size_t)N * 4);
  int*   offsets = (int*)alloc((size_t)(N + 1) * 4);
  int*   cursor  = (int*)alloc((size_t)N * 4);
  int*   bsums   = (int*)alloc(256 * 4);
  unsigned short* wph = (unsigned short*)alloc(2 * 128 * 128 * 2);
  unsigned short* wpl = (unsigned short*)alloc(2 * 128 * 128 * 2);
  (void)n_in; (void)out_size; (void)ws_size;

  hipMemsetAsync(deg, 0, (size_t)N * 4, stream);

  pack_w_k<<<128, 256, 0, stream>>>(Wl, Wr, wph, wpl);

  ln_gemm_mfma_k<<<(N + 63) / 64, 256, 0, stream>>>(x, gamma, beta, wph, wpl,
                                                    bl, br, xl, xr, N);

  degree_k<<<(E / 4 + 255) / 256, 256, 0, stream>>>(ei + E, deg, E);

  const int nb1 = (N + 1023) / 1024;
  scan1_k<<<nb1, 256, 0, stream>>>(deg, offsets, bsums, N);
  scan2_k<<<1, 128, 0, stream>>>(bsums, nb1);
  scan3_k<<<nb1, 256, 0, stream>>>(offsets, cursor, bsums, N, M);

  const int mx = (E > N ? E : N);
  fill_k<<<(mx / 4 + 255) / 256, 256, 0, stream>>>(ei, cursor, csr_src, E, N);

  agg_fused_k<<<(N + 3) / 4, 256, 0, stream>>>(xl, xr, att, csr_src, offsets,
                                               bias, out, N);
}